// Round 1
// baseline (7402.177 us; speedup 1.0000x reference)
//
#include <hip/hip_runtime.h>
#include <hip/hip_bf16.h>

typedef __hip_bfloat16 bf16;

#define N_IMG   2048
#define F       64
#define EXPERTS 4
#define NBLK    4
#define CAP     768
#define CLS_CH  16
#define PAD_R   34
#define PAD_C   34
#define CH_STRIDE (PAD_R*PAD_C)        // 1156 elems per channel plane
#define ACT_CH   67                    // 64 activation channels + 3 image channels
#define LDS_ELEMS (ACT_CH*CH_STRIDE)   // 77452 bf16 elems
#define LDS_BYTES (LDS_ELEMS*2)        // 154904 B  (<= 160 KiB/WG)
#define OUT_PER_IMG (3*64*64)          // 12288

// ---------------- classifier: conv3x3(3->16) + relu + mean + fc + argmax ----------
__global__ __launch_bounds__(256) void k_classify(
    const float* __restrict__ inp, const float* __restrict__ w1,
    const float* __restrict__ b1, const float* __restrict__ wfc,
    const float* __restrict__ bfc, int* __restrict__ expert)
{
    __shared__ float img[3*1024];
    __shared__ float partial[CLS_CH][16];
    __shared__ float meanf[CLS_CH];
    const int n = blockIdx.x, t = threadIdx.x;
    const float* src = inp + (size_t)n*3072;
    for (int i = t; i < 3072; i += 256) img[i] = src[i];
    __syncthreads();

    const int c = t >> 4, s = t & 15;
    const float bias = b1[c];
    float sum = 0.f;
    for (int k = 0; k < 64; ++k) {
        const int p = s*64 + k, y = p >> 5, x = p & 31;
        float o = bias;
        for (int ci = 0; ci < 3; ++ci) {
            const float* w  = w1 + (c*3 + ci)*9;
            const float* ip = img + ci*1024;
            #pragma unroll
            for (int dy = 0; dy < 3; ++dy) {
                const int py = y + dy - 1;
                if ((unsigned)py >= 32u) continue;
                #pragma unroll
                for (int dx = 0; dx < 3; ++dx) {
                    const int px = x + dx - 1;
                    if ((unsigned)px >= 32u) continue;
                    o += w[dy*3+dx] * ip[py*32 + px];
                }
            }
        }
        sum += fmaxf(o, 0.f);
    }
    partial[c][s] = sum;
    __syncthreads();
    if (t < CLS_CH) {
        float tot = 0.f;
        for (int i = 0; i < 16; ++i) tot += partial[t][i];
        meanf[t] = tot * (1.0f/1024.0f);
    }
    __syncthreads();
    if (t == 0) {
        float best = -1e30f; int bi = 0;
        for (int e = 0; e < EXPERTS; ++e) {
            float sc = bfc[e];
            for (int cc = 0; cc < CLS_CH; ++cc) sc += wfc[e*CLS_CH + cc] * meanf[cc];
            if (sc > best) { best = sc; bi = e; }   // strict >: first-max == jnp.argmax
        }
        expert[n] = bi;
    }
}

// ---------------- routing: ordered per-expert capacity scan --------------------
__global__ __launch_bounds__(256) void k_route(
    const int* __restrict__ expert, int* __restrict__ valid)
{
    __shared__ int se[N_IMG];
    __shared__ int sv[N_IMG];
    const int t = threadIdx.x;
    for (int i = t; i < N_IMG; i += 256) se[i] = expert[i];
    __syncthreads();
    if (t == 0) {
        int cnt[4] = {0,0,0,0};
        for (int n = 0; n < N_IMG; ++n) {
            const int e = se[n];
            sv[n] = (cnt[e] < CAP) ? 1 : 0;
            cnt[e]++;
        }
    }
    __syncthreads();
    for (int i = t; i < N_IMG; i += 256) valid[i] = sv[i];
}

// ---------------- SR trunk: head + 4 body blocks + skip + tail + pixel shuffle -----
// One workgroup per image; activations (64ch, zero-padded 34x34) + image (3ch) in LDS (bf16).
__global__ __launch_bounds__(1024) void k_sr(
    const float* __restrict__ inp,
    const float* __restrict__ head_w, const float* __restrict__ head_b,
    const float* __restrict__ body_w, const float* __restrict__ body_b,
    const float* __restrict__ tail_w, const float* __restrict__ tail_b,
    const int* __restrict__ expert, const int* __restrict__ valid,
    float* __restrict__ out)
{
    extern __shared__ bf16 lds[];
    const int n = blockIdx.x, t = threadIdx.x;
    float* outp = out + (size_t)n * OUT_PER_IMG;

    if (!valid[n]) {                       // over-capacity or none: output zeros
        #pragma unroll
        for (int k = 0; k < 12; ++k) outp[k*1024 + t] = 0.f;
        return;
    }
    const int e = expert[n];

    // zero entire LDS region (interior + pads)
    unsigned* ldsu = (unsigned*)lds;
    for (int i = t; i < LDS_ELEMS/2; i += 1024) ldsu[i] = 0u;
    __syncthreads();

    // stage image (bf16) into channels 64..66, padded layout
    const float* src = inp + (size_t)n*3072;
    #pragma unroll
    for (int k = 0; k < 3; ++k) {
        const int i = t + k*1024;
        const int ch = i >> 10, p = i & 1023, y = p >> 5, x = p & 31;
        lds[(64 + ch)*CH_STRIDE + (y+1)*PAD_C + (x+1)] = __float2bfloat16(src[i]);
    }
    __syncthreads();

    const int wv   = __builtin_amdgcn_readfirstlane(t >> 6);  // wave id 0..15 (SGPR)
    const int lane = t & 63;
    const int ly   = lane >> 5;            // 0/1: which of two rows per it
    const int x    = lane & 31;            // column
    const int c0   = wv*4;                 // this wave's first output channel

    float acc[64];                         // acc[it*4 + j], all static indices

    // ---- head: conv 3->64 (no relu), input = img channels 64..66
    {
        const float* wp = head_w + (size_t)e*F*27;
        const float* bp = head_b + e*F;
        #pragma unroll
        for (int it = 0; it < 16; ++it)
            #pragma unroll
            for (int j = 0; j < 4; ++j) acc[it*4+j] = bp[c0+j];
        #pragma unroll
        for (int dy = 0; dy < 3; ++dy)
        #pragma unroll
        for (int dx = 0; dx < 3; ++dx) {
            for (int ci = 0; ci < 3; ++ci) {
                const float w0 = wp[((c0+0)*3+ci)*9 + dy*3+dx];
                const float w1v = wp[((c0+1)*3+ci)*9 + dy*3+dx];
                const float w2 = wp[((c0+2)*3+ci)*9 + dy*3+dx];
                const float w3 = wp[((c0+3)*3+ci)*9 + dy*3+dx];
                const bf16* pa = lds + (64+ci)*CH_STRIDE + (ly+dy)*PAD_C + (x+dx);
                #pragma unroll
                for (int it = 0; it < 16; ++it) {
                    const float v = __bfloat162float(pa[it*68]);
                    acc[it*4+0] += v*w0; acc[it*4+1] += v*w1v;
                    acc[it*4+2] += v*w2; acc[it*4+3] += v*w3;
                }
            }
        }
        __syncthreads();
        #pragma unroll
        for (int it = 0; it < 16; ++it) {
            const int y = 2*it + ly;
            #pragma unroll
            for (int j = 0; j < 4; ++j)
                lds[(c0+j)*CH_STRIDE + (y+1)*PAD_C + (x+1)] = __float2bfloat16(acc[it*4+j]);
        }
        __syncthreads();
    }

    // ---- body blocks: relu(conv 64->64); last block adds recomputed h0
    for (int b = 0; b < NBLK; ++b) {
        const float* wp = body_w + (size_t)(e*NBLK + b)*F*F*9;
        const float* bp = body_b + (e*NBLK + b)*F;
        #pragma unroll
        for (int it = 0; it < 16; ++it)
            #pragma unroll
            for (int j = 0; j < 4; ++j) acc[it*4+j] = bp[c0+j];
        #pragma unroll
        for (int dy = 0; dy < 3; ++dy)
        #pragma unroll
        for (int dx = 0; dx < 3; ++dx) {
            const float* wt = wp + dy*3 + dx;
            for (int ci = 0; ci < 64; ++ci) {
                const float w0 = wt[((c0+0)*64+ci)*9];
                const float w1v = wt[((c0+1)*64+ci)*9];
                const float w2 = wt[((c0+2)*64+ci)*9];
                const float w3 = wt[((c0+3)*64+ci)*9];
                const bf16* pa = lds + ci*CH_STRIDE + (ly+dy)*PAD_C + (x+dx);
                #pragma unroll
                for (int it = 0; it < 16; ++it) {
                    const float v = __bfloat162float(pa[it*68]);
                    acc[it*4+0] += v*w0; acc[it*4+1] += v*w1v;
                    acc[it*4+2] += v*w2; acc[it*4+3] += v*w3;
                }
            }
        }
        __syncthreads();
        if (b < NBLK-1) {
            #pragma unroll
            for (int it = 0; it < 16; ++it) {
                const int y = 2*it + ly;
                #pragma unroll
                for (int j = 0; j < 4; ++j)
                    lds[(c0+j)*CH_STRIDE + (y+1)*PAD_C + (x+1)] =
                        __float2bfloat16(fmaxf(acc[it*4+j], 0.f));
            }
        } else {
            // h = relu(conv) + h0, h0 recomputed from staged image (fp32 accum)
            const float* hwp = head_w + (size_t)e*F*27;
            const float* hbp = head_b + e*F;
            #pragma unroll
            for (int it = 0; it < 16; ++it) {
                const int y = 2*it + ly;
                #pragma unroll
                for (int j = 0; j < 4; ++j) {
                    float h0 = hbp[c0+j];
                    for (int ci = 0; ci < 3; ++ci) {
                        const bf16* pi  = lds + (64+ci)*CH_STRIDE;
                        const float* hw = hwp + ((c0+j)*3+ci)*9;
                        #pragma unroll
                        for (int dy = 0; dy < 3; ++dy)
                            #pragma unroll
                            for (int dx = 0; dx < 3; ++dx)
                                h0 += hw[dy*3+dx] *
                                      __bfloat162float(pi[(y+dy)*PAD_C + (x+dx)]);
                    }
                    lds[(c0+j)*CH_STRIDE + (y+1)*PAD_C + (x+1)] =
                        __float2bfloat16(fmaxf(acc[it*4+j], 0.f) + h0);
                }
            }
        }
        __syncthreads();
    }

    // ---- tail: conv 64->12 + pixel_shuffle(2), fused: compute each output pixel
    {
        const float* wp = tail_w + (size_t)e*12*F*9;
        const float* bp = tail_b + e*12;
        for (int k = 0; k < 12; ++k) {
            const int oidx = k*1024 + t;
            const int co = oidx >> 12, rem = oidx & 4095;
            const int yo = rem >> 6, xo = rem & 63;
            const int tc = co*4 + (yo & 1)*2 + (xo & 1);
            const int ys = yo >> 1, xs = xo >> 1;
            float a = bp[tc];
            const float* wt = wp + tc*F*9;
            for (int ci = 0; ci < 64; ++ci) {
                const bf16* pa = lds + ci*CH_STRIDE + ys*PAD_C + xs;
                const float* w9 = wt + ci*9;
                #pragma unroll
                for (int dy = 0; dy < 3; ++dy)
                    #pragma unroll
                    for (int dx = 0; dx < 3; ++dx)
                        a += w9[dy*3+dx] * __bfloat162float(pa[dy*PAD_C + dx]);
            }
            outp[oidx] = a;
        }
    }
}

extern "C" void kernel_launch(void* const* d_in, const int* in_sizes, int n_in,
                              void* d_out, int out_size, void* d_ws, size_t ws_size,
                              hipStream_t stream) {
    const float* inp     = (const float*)d_in[0];
    const float* cls_w1  = (const float*)d_in[1];
    const float* cls_b1  = (const float*)d_in[2];
    const float* cls_wfc = (const float*)d_in[3];
    const float* cls_bfc = (const float*)d_in[4];
    const float* head_w  = (const float*)d_in[5];
    const float* head_b  = (const float*)d_in[6];
    const float* body_w  = (const float*)d_in[7];
    const float* body_b  = (const float*)d_in[8];
    const float* tail_w  = (const float*)d_in[9];
    const float* tail_b  = (const float*)d_in[10];
    float* out = (float*)d_out;

    int* expert = (int*)d_ws;
    int* valid  = expert + N_IMG;

    // allow >64KB dynamic LDS (idempotent, not a stream op -> graph-capture safe)
    hipFuncSetAttribute((const void*)k_sr,
                        hipFuncAttributeMaxDynamicSharedMemorySize, LDS_BYTES);

    k_classify<<<N_IMG, 256, 0, stream>>>(inp, cls_w1, cls_b1, cls_wfc, cls_bfc, expert);
    k_route<<<1, 256, 0, stream>>>(expert, valid);
    k_sr<<<N_IMG, 1024, LDS_BYTES, stream>>>(inp, head_w, head_b, body_w, body_b,
                                             tail_w, tail_b, expert, valid, out);
}

// Round 2
// 1432.745 us; speedup vs baseline: 5.1664x; 5.1664x over previous
//
#include <hip/hip_runtime.h>
#include <hip/hip_bf16.h>

typedef unsigned short u16;
typedef short s8v __attribute__((ext_vector_type(8)));
typedef float f16v __attribute__((ext_vector_type(16)));

#define N_IMG   2048
#define F       64
#define EXPERTS 4
#define NBLK    4
#define CAP     768
#define CLS_CH  16
#define OUT_PER_IMG (3*64*64)

// LDS layout
#define ACT_BYTES (1156*64*2)          // 147968: [pix 34*34][64ch] bf16, swizzled
#define IMG_OFF   ACT_BYTES
#define IMG_BYTES (1156*4*2)           // 9248: [pix][4ch] bf16 (ch3 = 0)
#define LDS_BYTES (ACT_BYTES + IMG_BYTES)   // 157216 <= 160 KiB

// act swizzle: pixel p (0..1155), channel-byte c (0..127), 16B-slot XOR
#define SWZB(p, c) (((p) << 7) + ((c) ^ (((p) & 7) << 4)))

// ws layout (bytes)
#define WS_EXPERT   0
#define WS_VALID    8192
#define WS_BODY     16384                       // [e][b][tap][64 oc][64 ci] bf16
#define WS_HEAD     (WS_BODY + 589824*2)        // [e][64 oc][64 k] bf16 (k=tap*4+ci, 0-pad)
#define WS_TAIL     (WS_HEAD + 16384*2)         // [e][tap][32 oc][64 ci] bf16 (oc>=12 -> 0)

__device__ __forceinline__ u16 f2bf(float v) {
    return __builtin_bit_cast(u16, __float2bfloat16(v));
}
__device__ __forceinline__ unsigned pk2(float a, float b) {
    return (unsigned)f2bf(a) | ((unsigned)f2bf(b) << 16);
}

// ---------------- weight prep: fp32 -> bf16, MFMA layouts --------------------
__global__ __launch_bounds__(256) void k_prep(
    const float* __restrict__ hw, const float* __restrict__ bw,
    const float* __restrict__ tw, u16* __restrict__ oh,
    u16* __restrict__ ob, u16* __restrict__ otl)
{
    const int i = blockIdx.x * 256 + threadIdx.x;
    if (i < 589824) {                       // body: [lb][tap][oc][ci] <- bw[lb][oc][ci][tap]
        const int ci = i & 63, oc = (i >> 6) & 63, tap = (i >> 12) % 9, lb = i / (9*4096);
        ob[i] = f2bf(bw[((lb*64 + oc)*64 + ci)*9 + tap]);
    } else if (i < 589824 + 16384) {        // head: [e][oc][k], k=tap*4+ci
        const int j = i - 589824;
        const int k = j & 63, oc = (j >> 6) & 63, e = j >> 12;
        const int tap = k >> 2, ci = k & 3;
        const float v = (k < 36 && ci < 3) ? hw[((e*64 + oc)*3 + ci)*9 + tap] : 0.f;
        oh[j] = f2bf(v);
    } else if (i < 589824 + 16384 + 73728) {  // tail: [e][tap][32][64]
        const int j = i - 606208;
        const int ci = j & 63, oc = (j >> 6) & 31, tap = (j >> 11) % 9, e = j / (9*2048);
        const float v = (oc < 12) ? tw[((e*12 + oc)*64 + ci)*9 + tap] : 0.f;
        otl[j] = f2bf(v);
    }
}

// ---------------- classifier (unchanged from round 1) ------------------------
__global__ __launch_bounds__(256) void k_classify(
    const float* __restrict__ inp, const float* __restrict__ w1,
    const float* __restrict__ b1, const float* __restrict__ wfc,
    const float* __restrict__ bfc, int* __restrict__ expert)
{
    __shared__ float img[3*1024];
    __shared__ float partial[CLS_CH][16];
    __shared__ float meanf[CLS_CH];
    const int n = blockIdx.x, t = threadIdx.x;
    const float* src = inp + (size_t)n*3072;
    for (int i = t; i < 3072; i += 256) img[i] = src[i];
    __syncthreads();

    const int c = t >> 4, s = t & 15;
    const float bias = b1[c];
    float sum = 0.f;
    for (int k = 0; k < 64; ++k) {
        const int p = s*64 + k, y = p >> 5, x = p & 31;
        float o = bias;
        for (int ci = 0; ci < 3; ++ci) {
            const float* w  = w1 + (c*3 + ci)*9;
            const float* ip = img + ci*1024;
            #pragma unroll
            for (int dy = 0; dy < 3; ++dy) {
                const int py = y + dy - 1;
                if ((unsigned)py >= 32u) continue;
                #pragma unroll
                for (int dx = 0; dx < 3; ++dx) {
                    const int px = x + dx - 1;
                    if ((unsigned)px >= 32u) continue;
                    o += w[dy*3+dx] * ip[py*32 + px];
                }
            }
        }
        sum += fmaxf(o, 0.f);
    }
    partial[c][s] = sum;
    __syncthreads();
    if (t < CLS_CH) {
        float tot = 0.f;
        for (int i = 0; i < 16; ++i) tot += partial[t][i];
        meanf[t] = tot * (1.0f/1024.0f);
    }
    __syncthreads();
    if (t == 0) {
        float best = -1e30f; int bi = 0;
        for (int e = 0; e < EXPERTS; ++e) {
            float sc = bfc[e];
            for (int cc = 0; cc < CLS_CH; ++cc) sc += wfc[e*CLS_CH + cc] * meanf[cc];
            if (sc > best) { best = sc; bi = e; }
        }
        expert[n] = bi;
    }
}

__global__ __launch_bounds__(256) void k_route(
    const int* __restrict__ expert, int* __restrict__ valid)
{
    __shared__ int se[N_IMG];
    __shared__ int sv[N_IMG];
    const int t = threadIdx.x;
    for (int i = t; i < N_IMG; i += 256) se[i] = expert[i];
    __syncthreads();
    if (t == 0) {
        int cnt[4] = {0,0,0,0};
        for (int n = 0; n < N_IMG; ++n) {
            const int e = se[n];
            sv[n] = (cnt[e] < CAP) ? 1 : 0;
            cnt[e]++;
        }
    }
    __syncthreads();
    for (int i = t; i < N_IMG; i += 256) valid[i] = sv[i];
}

// ---------------- MFMA building blocks --------------------------------------
__device__ __forceinline__ s8v ld_act(const char* actb, int p, int c) {
    return *reinterpret_cast<const s8v*>(actb + SWZB(p, c));
}
__device__ __forceinline__ s8v ld_w(const u16* w, int eoff) {
    return *reinterpret_cast<const s8v*>(w + eoff);
}

// init acc[2][2] (oc-tile, px-tile) from per-channel bias (64 floats)
__device__ __forceinline__ void bias_init(f16v acc[2][2], const float* bp, int h) {
    #pragma unroll
    for (int ot = 0; ot < 2; ++ot)
        #pragma unroll
        for (int g = 0; g < 4; ++g) {
            const float4 bv = *reinterpret_cast<const float4*>(bp + ot*32 + g*8 + h*4);
            const float* b4 = (const float*)&bv;
            #pragma unroll
            for (int i = 0; i < 4; ++i) {
                acc[ot][0][g*4+i] = b4[i];
                acc[ot][1][g*4+i] = b4[i];
            }
        }
}
__device__ __forceinline__ void bias_add(f16v acc[2][2], const float* bp, int h) {
    #pragma unroll
    for (int ot = 0; ot < 2; ++ot)
        #pragma unroll
        for (int g = 0; g < 4; ++g) {
            const float4 bv = *reinterpret_cast<const float4*>(bp + ot*32 + g*8 + h*4);
            const float* b4 = (const float*)&bv;
            #pragma unroll
            for (int i = 0; i < 4; ++i) {
                acc[ot][0][g*4+i] += b4[i];
                acc[ot][1][g*4+i] += b4[i];
            }
        }
}

// body conv GEMM: K = 9 taps x 64ci, acc += W * act
__device__ __forceinline__ void body_gemm(f16v acc[2][2], const char* actb,
                                          const u16* wb, int r31, int h, int y0) {
    for (int tap = 0; tap < 9; ++tap) {
        const int dy = tap / 3, dx = tap % 3;
        const int p0 = (y0 + dy)*34 + r31 + dx;
        #pragma unroll
        for (int kc = 0; kc < 4; ++kc) {
            const s8v w0 = ld_w(wb, (tap*64 + r31)*64      + kc*16 + h*8);
            const s8v w1 = ld_w(wb, (tap*64 + 32 + r31)*64 + kc*16 + h*8);
            const s8v a0 = ld_act(actb, p0,      kc*32 + h*16);
            const s8v a1 = ld_act(actb, p0 + 34, kc*32 + h*16);
            acc[0][0] = __builtin_amdgcn_mfma_f32_32x32x16_bf16(w0, a0, acc[0][0], 0,0,0);
            acc[1][0] = __builtin_amdgcn_mfma_f32_32x32x16_bf16(w1, a0, acc[1][0], 0,0,0);
            acc[0][1] = __builtin_amdgcn_mfma_f32_32x32x16_bf16(w0, a1, acc[0][1], 0,0,0);
            acc[1][1] = __builtin_amdgcn_mfma_f32_32x32x16_bf16(w1, a1, acc[1][1], 0,0,0);
        }
    }
}

// head conv GEMM (3ch image, K = tap*4+ci zero-padded to 48)
__device__ __forceinline__ void head_gemm(f16v acc[2][2], const char* imgb,
                                          const u16* hw, int r31, int h, int y0) {
    #pragma unroll
    for (int kc = 0; kc < 3; ++kc) {
        const s8v w0 = ld_w(hw, r31*64        + kc*16 + h*8);
        const s8v w1 = ld_w(hw, (32 + r31)*64 + kc*16 + h*8);
        #pragma unroll
        for (int pt = 0; pt < 2; ++pt) {
            const int y = y0 + pt;
            const int tA = kc*4 + h*2, tB = tA + 1;
            const int pA = (tA <= 8) ? (y + tA/3)*34 + r31 + (tA % 3) : 0;
            const int pB = (tB <= 8) ? (y + tB/3)*34 + r31 + (tB % 3) : 0;
            const uint2 lo = *reinterpret_cast<const uint2*>(imgb + pA*8);
            const uint2 hi = *reinterpret_cast<const uint2*>(imgb + pB*8);
            uint4 tmp; tmp.x = lo.x; tmp.y = lo.y; tmp.z = hi.x; tmp.w = hi.y;
            const s8v bf = __builtin_bit_cast(s8v, tmp);
            acc[0][pt] = __builtin_amdgcn_mfma_f32_32x32x16_bf16(w0, bf, acc[0][pt], 0,0,0);
            acc[1][pt] = __builtin_amdgcn_mfma_f32_32x32x16_bf16(w1, bf, acc[1][pt], 0,0,0);
        }
    }
}

// write acc -> act LDS (bf16, swizzled). C/D row = (reg&3)+8*(reg>>2)+4*h, col = r31
__device__ __forceinline__ void st_act(char* actb, const f16v acc[2][2],
                                       int r31, int h, int y0) {
    #pragma unroll
    for (int pt = 0; pt < 2; ++pt) {
        const int p = (y0 + pt + 1)*34 + r31 + 1;
        #pragma unroll
        for (int ot = 0; ot < 2; ++ot)
            #pragma unroll
            for (int g = 0; g < 4; ++g) {
                uint2 wv;
                wv.x = pk2(acc[ot][pt][g*4+0], acc[ot][pt][g*4+1]);
                wv.y = pk2(acc[ot][pt][g*4+2], acc[ot][pt][g*4+3]);
                *reinterpret_cast<uint2*>(actb + SWZB(p, ot*64 + g*16 + h*8)) = wv;
            }
    }
}

// ---------------- SR trunk (MFMA) --------------------------------------------
__global__ __launch_bounds__(1024) void k_sr(
    const float* __restrict__ inp,
    const float* __restrict__ head_b, const float* __restrict__ body_b,
    const float* __restrict__ tail_b,
    const u16* __restrict__ bw_head, const u16* __restrict__ bw_body,
    const u16* __restrict__ bw_tail,
    const int* __restrict__ expert, const int* __restrict__ valid,
    float* __restrict__ out)
{
    extern __shared__ char lds[];
    char* actb = lds;
    char* imgb = lds + IMG_OFF;
    const int n = blockIdx.x, t = threadIdx.x;
    float* outp = out + (size_t)n * OUT_PER_IMG;

    if (!valid[n]) {
        #pragma unroll
        for (int k = 0; k < 12; ++k) outp[k*1024 + t] = 0.f;
        return;
    }
    const int e = expert[n];

    // zero act + img (incl. all pads)
    for (int i = t; i < LDS_BYTES/4; i += 1024) ((unsigned*)lds)[i] = 0u;
    __syncthreads();

    // stage image bf16 -> [pix][4]
    const float* src = inp + (size_t)n*3072;
    #pragma unroll
    for (int k = 0; k < 3; ++k) {
        const int i = t + k*1024;
        const int ci = i >> 10, p = i & 1023, y = p >> 5, x = p & 31;
        ((u16*)imgb)[((y+1)*34 + x + 1)*4 + ci] = f2bf(src[i]);
    }
    __syncthreads();

    const int lane = t & 63, wv = t >> 6;
    const int r31 = lane & 31, h = lane >> 5;
    const int y0 = wv * 2;

    const u16* hw = bw_head + e*4096;
    const float* hb = head_b + e*64;

    f16v acc[2][2];

    // ---- head
    bias_init(acc, hb, h);
    head_gemm(acc, imgb, hw, r31, h, y0);
    st_act(actb, acc, r31, h, y0);          // img staged & act zeroed behind barrier
    __syncthreads();

    // ---- body blocks
    for (int b = 0; b < NBLK; ++b) {
        const u16* wb = bw_body + (size_t)(e*NBLK + b)*9*64*64;
        bias_init(acc, body_b + (e*NBLK + b)*64, h);
        body_gemm(acc, actb, wb, r31, h, y0);
        // relu
        #pragma unroll
        for (int ot = 0; ot < 2; ++ot)
            #pragma unroll
            for (int pt = 0; pt < 2; ++pt)
                #pragma unroll
                for (int i = 0; i < 16; ++i)
                    acc[ot][pt][i] = fmaxf(acc[ot][pt][i], 0.f);
        if (b == NBLK-1) {                  // + h0 (recomputed from staged image)
            bias_add(acc, hb, h);
            head_gemm(acc, imgb, hw, r31, h, y0);
        }
        __syncthreads();                    // all reads of old act done
        st_act(actb, acc, r31, h, y0);
        __syncthreads();
    }

    // ---- tail: conv 64->12 (padded to 32) + pixel shuffle
    {
        const u16* tw = bw_tail + e*(9*32*64);
        const float* tb = tail_b + e*12;
        f16v tacc[2];
        #pragma unroll
        for (int pt = 0; pt < 2; ++pt)
            #pragma unroll
            for (int g = 0; g < 4; ++g)
                #pragma unroll
                for (int i = 0; i < 4; ++i) {
                    const int tc = g*8 + h*4 + i;
                    tacc[pt][g*4+i] = (tc < 12) ? tb[tc] : 0.f;
                }
        for (int tap = 0; tap < 9; ++tap) {
            const int dy = tap / 3, dx = tap % 3;
            const int p0 = (y0 + dy)*34 + r31 + dx;
            #pragma unroll
            for (int kc = 0; kc < 4; ++kc) {
                const s8v twf = ld_w(tw, (tap*32 + r31)*64 + kc*16 + h*8);
                const s8v a0 = ld_act(actb, p0,      kc*32 + h*16);
                const s8v a1 = ld_act(actb, p0 + 34, kc*32 + h*16);
                tacc[0] = __builtin_amdgcn_mfma_f32_32x32x16_bf16(twf, a0, tacc[0], 0,0,0);
                tacc[1] = __builtin_amdgcn_mfma_f32_32x32x16_bf16(twf, a1, tacc[1], 0,0,0);
            }
        }
        // pixel-shuffle store: tc = g*8+h*4+i, px = (y0+pt, r31)
        #pragma unroll
        for (int pt = 0; pt < 2; ++pt) {
            const int ys = y0 + pt;
            #pragma unroll
            for (int g = 0; g < 2; ++g)        // g>=2 -> tc>=16, all invalid
                #pragma unroll
                for (int i = 0; i < 4; ++i) {
                    const int tc = g*8 + h*4 + i;
                    if (tc < 12) {
                        const int co = tc >> 2;
                        const int yo = 2*ys + ((tc >> 1) & 1);
                        const int xo = 2*r31 + (tc & 1);
                        outp[co*4096 + yo*64 + xo] = tacc[pt][g*4+i];
                    }
                }
        }
    }
}

extern "C" void kernel_launch(void* const* d_in, const int* in_sizes, int n_in,
                              void* d_out, int out_size, void* d_ws, size_t ws_size,
                              hipStream_t stream) {
    const float* inp     = (const float*)d_in[0];
    const float* cls_w1  = (const float*)d_in[1];
    const float* cls_b1  = (const float*)d_in[2];
    const float* cls_wfc = (const float*)d_in[3];
    const float* cls_bfc = (const float*)d_in[4];
    const float* head_w  = (const float*)d_in[5];
    const float* head_b  = (const float*)d_in[6];
    const float* body_w  = (const float*)d_in[7];
    const float* body_b  = (const float*)d_in[8];
    const float* tail_w  = (const float*)d_in[9];
    const float* tail_b  = (const float*)d_in[10];
    float* out = (float*)d_out;

    char* ws = (char*)d_ws;
    int* expert = (int*)(ws + WS_EXPERT);
    int* valid  = (int*)(ws + WS_VALID);
    u16* bw_body = (u16*)(ws + WS_BODY);
    u16* bw_head = (u16*)(ws + WS_HEAD);
    u16* bw_tail = (u16*)(ws + WS_TAIL);

    hipFuncSetAttribute((const void*)k_sr,
                        hipFuncAttributeMaxDynamicSharedMemorySize, LDS_BYTES);

    k_prep<<<(679936 + 255)/256, 256, 0, stream>>>(head_w, body_w, tail_w,
                                                   bw_head, bw_body, bw_tail);
    k_classify<<<N_IMG, 256, 0, stream>>>(inp, cls_w1, cls_b1, cls_wfc, cls_bfc, expert);
    k_route<<<1, 256, 0, stream>>>(expert, valid);
    k_sr<<<N_IMG, 1024, LDS_BYTES, stream>>>(inp, head_b, body_b, tail_b,
                                             bw_head, bw_body, bw_tail,
                                             expert, valid, out);
}

// Round 3
// 786.309 us; speedup vs baseline: 9.4138x; 1.8221x over previous
//
#include <hip/hip_runtime.h>
#include <hip/hip_bf16.h>

typedef unsigned short u16;
typedef short s8v __attribute__((ext_vector_type(8)));
typedef float f16v __attribute__((ext_vector_type(16)));

#define N_IMG   2048
#define F       64
#define EXPERTS 4
#define NBLK    4
#define CAP     768
#define CLS_CH  16
#define OUT_PER_IMG (3*64*64)

// LDS layout (k_sr)
#define ACT_BYTES (1156*64*2)          // 147968: [pix 34*34][64ch] bf16, swizzled
#define IMG_OFF   ACT_BYTES
#define IMG_BYTES (1156*4*2)           // 9248: [pix][4ch] bf16 (ch3 = 0)
#define LDS_BYTES (ACT_BYTES + IMG_BYTES)   // 157216 <= 160 KiB

// act swizzle: pixel p (0..1155), channel-byte c (0..127), 16B-slot XOR
#define SWZB(p, c) (((p) << 7) + ((c) ^ (((p) & 7) << 4)))

// ws layout (bytes)
#define WS_EXPERT   0
#define WS_VALID    8192
#define WS_BODY     16384                       // [e][b][tap][64 oc][64 ci] bf16
#define WS_HEAD     (WS_BODY + 589824*2)        // [e][64 oc][64 k] bf16 (k=tap*4+ci, 0-pad)
#define WS_TAIL     (WS_HEAD + 16384*2)         // [e][tap][32 oc][64 ci] bf16 (oc>=12 -> 0)

__device__ __forceinline__ u16 f2bf(float v) {
    return __builtin_bit_cast(u16, __float2bfloat16(v));
}
__device__ __forceinline__ unsigned pk2(float a, float b) {
    return (unsigned)f2bf(a) | ((unsigned)f2bf(b) << 16);
}

// ---------------- weight prep: fp32 -> bf16, MFMA layouts --------------------
__global__ __launch_bounds__(256) void k_prep(
    const float* __restrict__ hw, const float* __restrict__ bw,
    const float* __restrict__ tw, u16* __restrict__ oh,
    u16* __restrict__ ob, u16* __restrict__ otl)
{
    const int i = blockIdx.x * 256 + threadIdx.x;
    if (i < 589824) {                       // body: [lb][tap][oc][ci] <- bw[lb][oc][ci][tap]
        const int ci = i & 63, oc = (i >> 6) & 63, tap = (i >> 12) % 9, lb = i / (9*4096);
        ob[i] = f2bf(bw[((lb*64 + oc)*64 + ci)*9 + tap]);
    } else if (i < 589824 + 16384) {        // head: [e][oc][k], k=tap*4+ci
        const int j = i - 589824;
        const int k = j & 63, oc = (j >> 6) & 63, e = j >> 12;
        const int tap = k >> 2, ci = k & 3;
        const float v = (k < 36 && ci < 3) ? hw[((e*64 + oc)*3 + ci)*9 + tap] : 0.f;
        oh[j] = f2bf(v);
    } else if (i < 589824 + 16384 + 73728) {  // tail: [e][tap][32][64]
        const int j = i - 606208;
        const int ci = j & 63, oc = (j >> 6) & 31, tap = (j >> 11) % 9, e = j / (9*2048);
        const float v = (oc < 12) ? tw[((e*12 + oc)*64 + ci)*9 + tap] : 0.f;
        otl[j] = f2bf(v);
    }
}

// ---------------- classifier: conflict-free rewrite ---------------------------
// Thread t owns pixels {t, t+256, t+512, t+768} (stride-1 across lanes).
// Neighborhood -> VGPRs once per pixel; weights via uniform global reads (s_load).
__global__ __launch_bounds__(256) void k_classify(
    const float* __restrict__ inp, const float* __restrict__ w1,
    const float* __restrict__ b1, const float* __restrict__ wfc,
    const float* __restrict__ bfc, int* __restrict__ expert)
{
    __shared__ float img[3*1024];
    __shared__ float wred[4][CLS_CH];
    __shared__ float meanf[CLS_CH];
    const int n = blockIdx.x, t = threadIdx.x;
    const float* src = inp + (size_t)n*3072;
    {   // vectorized stage: 3072 floats = 768 float4
        const float4* s4 = (const float4*)src;
        float4* d4 = (float4*)img;
        for (int i = t; i < 768; i += 256) d4[i] = s4[i];
    }
    __syncthreads();

    float sums[CLS_CH];
    #pragma unroll
    for (int c = 0; c < CLS_CH; ++c) sums[c] = 0.f;

    #pragma unroll
    for (int k4 = 0; k4 < 4; ++k4) {
        const int p = t + k4*256, y = p >> 5, x = p & 31;
        float v[27];
        #pragma unroll
        for (int ci = 0; ci < 3; ++ci)
            #pragma unroll
            for (int dy = 0; dy < 3; ++dy)
                #pragma unroll
                for (int dx = 0; dx < 3; ++dx) {
                    const int py = y + dy - 1, px = x + dx - 1;
                    v[ci*9 + dy*3 + dx] =
                        ((unsigned)py < 32u && (unsigned)px < 32u)
                            ? img[ci*1024 + py*32 + px] : 0.f;
                }
        for (int c = 0; c < CLS_CH; ++c) {      // rolled: 27 s_loads per iter
            float o = b1[c];
            #pragma unroll
            for (int k = 0; k < 27; ++k) o += w1[c*27 + k] * v[k];
            sums[c] += fmaxf(o, 0.f);
        }
    }

    // wave butterfly reduce (width 64), then cross-wave via LDS
    #pragma unroll
    for (int c = 0; c < CLS_CH; ++c) {
        float s = sums[c];
        #pragma unroll
        for (int m = 32; m >= 1; m >>= 1) s += __shfl_xor(s, m);
        sums[c] = s;
    }
    const int lane = t & 63, wv = t >> 6;
    if (lane == 0)
        #pragma unroll
        for (int c = 0; c < CLS_CH; ++c) wred[wv][c] = sums[c];
    __syncthreads();
    if (t < CLS_CH)
        meanf[t] = (wred[0][t] + wred[1][t] + wred[2][t] + wred[3][t]) * (1.0f/1024.0f);
    __syncthreads();
    if (t == 0) {
        float best = -1e30f; int bi = 0;
        for (int e = 0; e < EXPERTS; ++e) {
            float sc = bfc[e];
            for (int cc = 0; cc < CLS_CH; ++cc) sc += wfc[e*CLS_CH + cc] * meanf[cc];
            if (sc > best) { best = sc; bi = e; }   // strict >: first-max == jnp.argmax
        }
        expert[n] = bi;
    }
}

__global__ __launch_bounds__(256) void k_route(
    const int* __restrict__ expert, int* __restrict__ valid)
{
    __shared__ int se[N_IMG];
    __shared__ int sv[N_IMG];
    const int t = threadIdx.x;
    for (int i = t; i < N_IMG; i += 256) se[i] = expert[i];
    __syncthreads();
    if (t == 0) {
        int cnt[4] = {0,0,0,0};
        for (int n = 0; n < N_IMG; ++n) {
            const int e = se[n];
            sv[n] = (cnt[e] < CAP) ? 1 : 0;
            cnt[e]++;
        }
    }
    __syncthreads();
    for (int i = t; i < N_IMG; i += 256) valid[i] = sv[i];
}

// ---------------- MFMA building blocks --------------------------------------
__device__ __forceinline__ s8v ld_act(const char* actb, int p, int c) {
    return *reinterpret_cast<const s8v*>(actb + SWZB(p, c));
}
__device__ __forceinline__ s8v ld_w(const u16* w, int eoff) {
    return *reinterpret_cast<const s8v*>(w + eoff);
}

// init acc[2][2] (oc-tile, px-tile) from per-channel bias (64 floats)
__device__ __forceinline__ void bias_init(f16v acc[2][2], const float* bp, int h) {
    #pragma unroll
    for (int ot = 0; ot < 2; ++ot)
        #pragma unroll
        for (int g = 0; g < 4; ++g) {
            const float4 bv = *reinterpret_cast<const float4*>(bp + ot*32 + g*8 + h*4);
            const float* b4 = (const float*)&bv;
            #pragma unroll
            for (int i = 0; i < 4; ++i) {
                acc[ot][0][g*4+i] = b4[i];
                acc[ot][1][g*4+i] = b4[i];
            }
        }
}
__device__ __forceinline__ void bias_add(f16v acc[2][2], const float* bp, int h) {
    #pragma unroll
    for (int ot = 0; ot < 2; ++ot)
        #pragma unroll
        for (int g = 0; g < 4; ++g) {
            const float4 bv = *reinterpret_cast<const float4*>(bp + ot*32 + g*8 + h*4);
            const float* b4 = (const float*)&bv;
            #pragma unroll
            for (int i = 0; i < 4; ++i) {
                acc[ot][0][g*4+i] += b4[i];
                acc[ot][1][g*4+i] += b4[i];
            }
        }
}

// body conv GEMM: K = 9 taps x 64ci, acc += W * act
__device__ __forceinline__ void body_gemm(f16v acc[2][2], const char* actb,
                                          const u16* wb, int r31, int h, int y0) {
    for (int tap = 0; tap < 9; ++tap) {
        const int dy = tap / 3, dx = tap % 3;
        const int p0 = (y0 + dy)*34 + r31 + dx;
        #pragma unroll
        for (int kc = 0; kc < 4; ++kc) {
            const s8v w0 = ld_w(wb, (tap*64 + r31)*64      + kc*16 + h*8);
            const s8v w1 = ld_w(wb, (tap*64 + 32 + r31)*64 + kc*16 + h*8);
            const s8v a0 = ld_act(actb, p0,      kc*32 + h*16);
            const s8v a1 = ld_act(actb, p0 + 34, kc*32 + h*16);
            acc[0][0] = __builtin_amdgcn_mfma_f32_32x32x16_bf16(w0, a0, acc[0][0], 0,0,0);
            acc[1][0] = __builtin_amdgcn_mfma_f32_32x32x16_bf16(w1, a0, acc[1][0], 0,0,0);
            acc[0][1] = __builtin_amdgcn_mfma_f32_32x32x16_bf16(w0, a1, acc[0][1], 0,0,0);
            acc[1][1] = __builtin_amdgcn_mfma_f32_32x32x16_bf16(w1, a1, acc[1][1], 0,0,0);
        }
    }
}

// head conv GEMM (3ch image, K = tap*4+ci zero-padded to 48)
__device__ __forceinline__ void head_gemm(f16v acc[2][2], const char* imgb,
                                          const u16* hw, int r31, int h, int y0) {
    #pragma unroll
    for (int kc = 0; kc < 3; ++kc) {
        const s8v w0 = ld_w(hw, r31*64        + kc*16 + h*8);
        const s8v w1 = ld_w(hw, (32 + r31)*64 + kc*16 + h*8);
        #pragma unroll
        for (int pt = 0; pt < 2; ++pt) {
            const int y = y0 + pt;
            const int tA = kc*4 + h*2, tB = tA + 1;
            const int pA = (tA <= 8) ? (y + tA/3)*34 + r31 + (tA % 3) : 0;
            const int pB = (tB <= 8) ? (y + tB/3)*34 + r31 + (tB % 3) : 0;
            const uint2 lo = *reinterpret_cast<const uint2*>(imgb + pA*8);
            const uint2 hi = *reinterpret_cast<const uint2*>(imgb + pB*8);
            uint4 tmp; tmp.x = lo.x; tmp.y = lo.y; tmp.z = hi.x; tmp.w = hi.y;
            const s8v bf = __builtin_bit_cast(s8v, tmp);
            acc[0][pt] = __builtin_amdgcn_mfma_f32_32x32x16_bf16(w0, bf, acc[0][pt], 0,0,0);
            acc[1][pt] = __builtin_amdgcn_mfma_f32_32x32x16_bf16(w1, bf, acc[1][pt], 0,0,0);
        }
    }
}

// write acc -> act LDS (bf16, swizzled). C/D row = (reg&3)+8*(reg>>2)+4*h, col = r31
__device__ __forceinline__ void st_act(char* actb, const f16v acc[2][2],
                                       int r31, int h, int y0) {
    #pragma unroll
    for (int pt = 0; pt < 2; ++pt) {
        const int p = (y0 + pt + 1)*34 + r31 + 1;
        #pragma unroll
        for (int ot = 0; ot < 2; ++ot)
            #pragma unroll
            for (int g = 0; g < 4; ++g) {
                uint2 wv;
                wv.x = pk2(acc[ot][pt][g*4+0], acc[ot][pt][g*4+1]);
                wv.y = pk2(acc[ot][pt][g*4+2], acc[ot][pt][g*4+3]);
                *reinterpret_cast<uint2*>(actb + SWZB(p, ot*64 + g*16 + h*8)) = wv;
            }
    }
}

// ---------------- SR trunk (MFMA) --------------------------------------------
__global__ __launch_bounds__(1024) void k_sr(
    const float* __restrict__ inp,
    const float* __restrict__ head_b, const float* __restrict__ body_b,
    const float* __restrict__ tail_b,
    const u16* __restrict__ bw_head, const u16* __restrict__ bw_body,
    const u16* __restrict__ bw_tail,
    const int* __restrict__ expert, const int* __restrict__ valid,
    float* __restrict__ out)
{
    extern __shared__ char lds[];
    char* actb = lds;
    char* imgb = lds + IMG_OFF;
    const int n = blockIdx.x, t = threadIdx.x;
    float* outp = out + (size_t)n * OUT_PER_IMG;

    if (!valid[n]) {
        #pragma unroll
        for (int k = 0; k < 12; ++k) outp[k*1024 + t] = 0.f;
        return;
    }
    const int e = expert[n];

    // zero act + img (incl. all pads)
    for (int i = t; i < LDS_BYTES/4; i += 1024) ((unsigned*)lds)[i] = 0u;
    __syncthreads();

    // stage image bf16 -> [pix][4]
    const float* src = inp + (size_t)n*3072;
    #pragma unroll
    for (int k = 0; k < 3; ++k) {
        const int i = t + k*1024;
        const int ci = i >> 10, p = i & 1023, y = p >> 5, x = p & 31;
        ((u16*)imgb)[((y+1)*34 + x + 1)*4 + ci] = f2bf(src[i]);
    }
    __syncthreads();

    const int lane = t & 63, wv = t >> 6;
    const int r31 = lane & 31, h = lane >> 5;
    const int y0 = wv * 2;

    const u16* hw = bw_head + e*4096;
    const float* hb = head_b + e*64;

    f16v acc[2][2];

    // ---- head
    bias_init(acc, hb, h);
    head_gemm(acc, imgb, hw, r31, h, y0);
    st_act(actb, acc, r31, h, y0);          // img staged & act zeroed behind barrier
    __syncthreads();

    // ---- body blocks
    for (int b = 0; b < NBLK; ++b) {
        const u16* wb = bw_body + (size_t)(e*NBLK + b)*9*64*64;
        bias_init(acc, body_b + (e*NBLK + b)*64, h);
        body_gemm(acc, actb, wb, r31, h, y0);
        // relu
        #pragma unroll
        for (int ot = 0; ot < 2; ++ot)
            #pragma unroll
            for (int pt = 0; pt < 2; ++pt)
                #pragma unroll
                for (int i = 0; i < 16; ++i)
                    acc[ot][pt][i] = fmaxf(acc[ot][pt][i], 0.f);
        if (b == NBLK-1) {                  // + h0 (recomputed from staged image)
            bias_add(acc, hb, h);
            head_gemm(acc, imgb, hw, r31, h, y0);
        }
        __syncthreads();                    // all reads of old act done
        st_act(actb, acc, r31, h, y0);
        __syncthreads();
    }

    // ---- tail: conv 64->12 (padded to 32) + pixel shuffle
    {
        const u16* tw = bw_tail + e*(9*32*64);
        const float* tb = tail_b + e*12;
        f16v tacc[2];
        #pragma unroll
        for (int pt = 0; pt < 2; ++pt)
            #pragma unroll
            for (int g = 0; g < 4; ++g)
                #pragma unroll
                for (int i = 0; i < 4; ++i) {
                    const int tc = g*8 + h*4 + i;
                    tacc[pt][g*4+i] = (tc < 12) ? tb[tc] : 0.f;
                }
        for (int tap = 0; tap < 9; ++tap) {
            const int dy = tap / 3, dx = tap % 3;
            const int p0 = (y0 + dy)*34 + r31 + dx;
            #pragma unroll
            for (int kc = 0; kc < 4; ++kc) {
                const s8v twf = ld_w(tw, (tap*32 + r31)*64 + kc*16 + h*8);
                const s8v a0 = ld_act(actb, p0,      kc*32 + h*16);
                const s8v a1 = ld_act(actb, p0 + 34, kc*32 + h*16);
                tacc[0] = __builtin_amdgcn_mfma_f32_32x32x16_bf16(twf, a0, tacc[0], 0,0,0);
                tacc[1] = __builtin_amdgcn_mfma_f32_32x32x16_bf16(twf, a1, tacc[1], 0,0,0);
            }
        }
        // pixel-shuffle store: tc = g*8+h*4+i, px = (y0+pt, r31)
        #pragma unroll
        for (int pt = 0; pt < 2; ++pt) {
            const int ys = y0 + pt;
            #pragma unroll
            for (int g = 0; g < 2; ++g)        // g>=2 -> tc>=16, all invalid
                #pragma unroll
                for (int i = 0; i < 4; ++i) {
                    const int tc = g*8 + h*4 + i;
                    if (tc < 12) {
                        const int co = tc >> 2;
                        const int yo = 2*ys + ((tc >> 1) & 1);
                        const int xo = 2*r31 + (tc & 1);
                        outp[co*4096 + yo*64 + xo] = tacc[pt][g*4+i];
                    }
                }
        }
    }
}

extern "C" void kernel_launch(void* const* d_in, const int* in_sizes, int n_in,
                              void* d_out, int out_size, void* d_ws, size_t ws_size,
                              hipStream_t stream) {
    const float* inp     = (const float*)d_in[0];
    const float* cls_w1  = (const float*)d_in[1];
    const float* cls_b1  = (const float*)d_in[2];
    const float* cls_wfc = (const float*)d_in[3];
    const float* cls_bfc = (const float*)d_in[4];
    const float* head_w  = (const float*)d_in[5];
    const float* head_b  = (const float*)d_in[6];
    const float* body_w  = (const float*)d_in[7];
    const float* body_b  = (const float*)d_in[8];
    const float* tail_w  = (const float*)d_in[9];
    const float* tail_b  = (const float*)d_in[10];
    float* out = (float*)d_out;

    char* ws = (char*)d_ws;
    int* expert = (int*)(ws + WS_EXPERT);
    int* valid  = (int*)(ws + WS_VALID);
    u16* bw_body = (u16*)(ws + WS_BODY);
    u16* bw_head = (u16*)(ws + WS_HEAD);
    u16* bw_tail = (u16*)(ws + WS_TAIL);

    hipFuncSetAttribute((const void*)k_sr,
                        hipFuncAttributeMaxDynamicSharedMemorySize, LDS_BYTES);

    k_prep<<<(679936 + 255)/256, 256, 0, stream>>>(head_w, body_w, tail_w,
                                                   bw_head, bw_body, bw_tail);
    k_classify<<<N_IMG, 256, 0, stream>>>(inp, cls_w1, cls_b1, cls_wfc, cls_bfc, expert);
    k_route<<<1, 256, 0, stream>>>(expert, valid);
    k_sr<<<N_IMG, 1024, LDS_BYTES, stream>>>(inp, head_b, body_b, tail_b,
                                             bw_head, bw_body, bw_tail,
                                             expert, valid, out);
}

// Round 4
// 698.708 us; speedup vs baseline: 10.5941x; 1.1254x over previous
//
#include <hip/hip_runtime.h>
#include <hip/hip_bf16.h>

typedef unsigned short u16;
typedef short s8v __attribute__((ext_vector_type(8)));
typedef float f16v __attribute__((ext_vector_type(16)));

#define N_IMG   2048
#define F       64
#define EXPERTS 4
#define NBLK    4
#define CAP     768
#define CLS_CH  16
#define OUT_PER_IMG (3*64*64)

// LDS layout (k_sr)
#define ACT_BYTES (1156*64*2)          // 147968: [pix 34*34][64ch] bf16, swizzled
#define IMG_OFF   ACT_BYTES
#define IMG_BYTES (1156*4*2)           // 9248: [pix][4ch] bf16 (ch3 = 0)
#define LDS_BYTES (ACT_BYTES + IMG_BYTES)   // 157216 <= 160 KiB

// act swizzle: pixel p (0..1155), channel-byte c (0..127), 16B-slot XOR
#define SWZB(p, c) (((p) << 7) + ((c) ^ (((p) & 7) << 4)))

// ws layout (bytes)
#define WS_EXPERT   0
#define WS_PERM     8192
#define WS_VLD      16384
#define WS_BODY     24576                       // [e][b][tap][64 oc][64 ci] bf16
#define WS_HEAD     (WS_BODY + 589824*2)        // [e][64 oc][64 k] bf16 (k=tap*4+ci, 0-pad)
#define WS_TAIL     (WS_HEAD + 16384*2)         // [e][tap][32 oc][64 ci] bf16 (oc>=12 -> 0)

__device__ __forceinline__ u16 f2bf(float v) {
    return __builtin_bit_cast(u16, __float2bfloat16(v));
}
__device__ __forceinline__ unsigned pk2(float a, float b) {
    return (unsigned)f2bf(a) | ((unsigned)f2bf(b) << 16);
}

// ---------------- weight prep: fp32 -> bf16, MFMA layouts --------------------
__global__ __launch_bounds__(256) void k_prep(
    const float* __restrict__ hw, const float* __restrict__ bw,
    const float* __restrict__ tw, u16* __restrict__ oh,
    u16* __restrict__ ob, u16* __restrict__ otl)
{
    const int i = blockIdx.x * 256 + threadIdx.x;
    if (i < 589824) {                       // body: [lb][tap][oc][ci] <- bw[lb][oc][ci][tap]
        const int ci = i & 63, oc = (i >> 6) & 63, tap = (i >> 12) % 9, lb = i / (9*4096);
        ob[i] = f2bf(bw[((lb*64 + oc)*64 + ci)*9 + tap]);
    } else if (i < 589824 + 16384) {        // head: [e][oc][k], k=tap*4+ci
        const int j = i - 589824;
        const int k = j & 63, oc = (j >> 6) & 63, e = j >> 12;
        const int tap = k >> 2, ci = k & 3;
        const float v = (k < 36 && ci < 3) ? hw[((e*64 + oc)*3 + ci)*9 + tap] : 0.f;
        oh[j] = f2bf(v);
    } else if (i < 589824 + 16384 + 73728) {  // tail: [e][tap][32][64]
        const int j = i - 606208;
        const int ci = j & 63, oc = (j >> 6) & 31, tap = (j >> 11) % 9, e = j / (9*2048);
        const float v = (oc < 12) ? tw[((e*12 + oc)*64 + ci)*9 + tap] : 0.f;
        otl[j] = f2bf(v);
    }
}

// ---------------- classifier ---------------------------------------------------
__global__ __launch_bounds__(256) void k_classify(
    const float* __restrict__ inp, const float* __restrict__ w1,
    const float* __restrict__ b1, const float* __restrict__ wfc,
    const float* __restrict__ bfc, int* __restrict__ expert)
{
    __shared__ float img[3*1024];
    __shared__ float wred[4][CLS_CH];
    __shared__ float meanf[CLS_CH];
    const int n = blockIdx.x, t = threadIdx.x;
    const float* src = inp + (size_t)n*3072;
    {   // vectorized stage: 3072 floats = 768 float4
        const float4* s4 = (const float4*)src;
        float4* d4 = (float4*)img;
        for (int i = t; i < 768; i += 256) d4[i] = s4[i];
    }
    __syncthreads();

    float sums[CLS_CH];
    #pragma unroll
    for (int c = 0; c < CLS_CH; ++c) sums[c] = 0.f;

    #pragma unroll
    for (int k4 = 0; k4 < 4; ++k4) {
        const int p = t + k4*256, y = p >> 5, x = p & 31;
        float v[27];
        #pragma unroll
        for (int ci = 0; ci < 3; ++ci)
            #pragma unroll
            for (int dy = 0; dy < 3; ++dy)
                #pragma unroll
                for (int dx = 0; dx < 3; ++dx) {
                    const int py = y + dy - 1, px = x + dx - 1;
                    v[ci*9 + dy*3 + dx] =
                        ((unsigned)py < 32u && (unsigned)px < 32u)
                            ? img[ci*1024 + py*32 + px] : 0.f;
                }
        for (int c = 0; c < CLS_CH; ++c) {      // rolled: 27 s_loads per iter
            float o = b1[c];
            #pragma unroll
            for (int k = 0; k < 27; ++k) o += w1[c*27 + k] * v[k];
            sums[c] += fmaxf(o, 0.f);
        }
    }

    #pragma unroll
    for (int c = 0; c < CLS_CH; ++c) {
        float s = sums[c];
        #pragma unroll
        for (int m = 32; m >= 1; m >>= 1) s += __shfl_xor(s, m);
        sums[c] = s;
    }
    const int lane = t & 63, wv = t >> 6;
    if (lane == 0)
        #pragma unroll
        for (int c = 0; c < CLS_CH; ++c) wred[wv][c] = sums[c];
    __syncthreads();
    if (t < CLS_CH)
        meanf[t] = (wred[0][t] + wred[1][t] + wred[2][t] + wred[3][t]) * (1.0f/1024.0f);
    __syncthreads();
    if (t == 0) {
        float best = -1e30f; int bi = 0;
        for (int e = 0; e < EXPERTS; ++e) {
            float sc = bfc[e];
            for (int cc = 0; cc < CLS_CH; ++cc) sc += wfc[e*CLS_CH + cc] * meanf[cc];
            if (sc > best) { best = sc; bi = e; }   // strict >: first-max == jnp.argmax
        }
        expert[n] = bi;
    }
}

// ---------------- routing: expert-sorted permutation (wave ballot-scan) -------
// slot order: [expert0 valid | e1 valid | e2 v | e3 v | overflow e0..e3]
// Order-preserving within each class; bijective over 2048 slots.
__global__ __launch_bounds__(256) void k_route(
    const int* __restrict__ expert, int* __restrict__ perm, int* __restrict__ vld)
{
    __shared__ int cnt[EXPERTS];
    __shared__ int vbase[EXPERTS], obase[EXPERTS];
    const int t = threadIdx.x;
    const int wv = t >> 6, lane = t & 63;     // wave wv handles expert wv

    // pass 1: per-expert totals
    int my = 0;
    for (int c = 0; c < N_IMG/64; ++c) {
        const int e = expert[c*64 + lane];
        const unsigned long long m = __ballot(e == wv);
        my += (int)__popcll(m);               // wave-uniform
    }
    if (lane == 0) cnt[wv] = my;
    __syncthreads();
    if (t == 0) {
        int vb = 0;
        for (int e = 0; e < EXPERTS; ++e) {
            vbase[e] = vb; vb += (cnt[e] < CAP ? cnt[e] : CAP);
        }
        int ob = vb;
        for (int e = 0; e < EXPERTS; ++e) {
            obase[e] = ob; ob += (cnt[e] > CAP ? cnt[e] - CAP : 0);
        }
    }
    __syncthreads();

    // pass 2: slot assignment
    int base = 0;
    for (int c = 0; c < N_IMG/64; ++c) {
        const int n = c*64 + lane;
        const int e = expert[n];
        const unsigned long long m = __ballot(e == wv);
        if (e == wv) {
            const int rank = base + (int)__popcll(m & ((1ull << lane) - 1ull));
            int slot, v;
            if (rank < CAP) { slot = vbase[wv] + rank;       v = 1; }
            else            { slot = obase[wv] + rank - CAP; v = 0; }
            perm[slot] = n; vld[slot] = v;
        }
        base += (int)__popcll(m);
    }
}

// ---------------- MFMA building blocks --------------------------------------
__device__ __forceinline__ s8v ld_act(const char* actb, int p, int c) {
    return *reinterpret_cast<const s8v*>(actb + SWZB(p, c));
}
__device__ __forceinline__ s8v ld_w(const u16* w, int eoff) {
    return *reinterpret_cast<const s8v*>(w + eoff);
}

// init acc[2][2] (oc-tile, px-tile) from per-channel bias (64 floats)
__device__ __forceinline__ void bias_init(f16v acc[2][2], const float* bp, int h) {
    #pragma unroll
    for (int ot = 0; ot < 2; ++ot)
        #pragma unroll
        for (int g = 0; g < 4; ++g) {
            const float4 bv = *reinterpret_cast<const float4*>(bp + ot*32 + g*8 + h*4);
            const float* b4 = (const float*)&bv;
            #pragma unroll
            for (int i = 0; i < 4; ++i) {
                acc[ot][0][g*4+i] = b4[i];
                acc[ot][1][g*4+i] = b4[i];
            }
        }
}
__device__ __forceinline__ void bias_add(f16v acc[2][2], const float* bp, int h) {
    #pragma unroll
    for (int ot = 0; ot < 2; ++ot)
        #pragma unroll
        for (int g = 0; g < 4; ++g) {
            const float4 bv = *reinterpret_cast<const float4*>(bp + ot*32 + g*8 + h*4);
            const float* b4 = (const float*)&bv;
            #pragma unroll
            for (int i = 0; i < 4; ++i) {
                acc[ot][0][g*4+i] += b4[i];
                acc[ot][1][g*4+i] += b4[i];
            }
        }
}

// body conv GEMM: K = 9 taps x 64ci, acc += W * act  (fully unrolled for prefetch)
__device__ __forceinline__ void body_gemm(f16v acc[2][2], const char* actb,
                                          const u16* wb, int r31, int h, int y0) {
    #pragma unroll
    for (int tap = 0; tap < 9; ++tap) {
        const int dy = tap / 3, dx = tap % 3;
        const int p0 = (y0 + dy)*34 + r31 + dx;
        #pragma unroll
        for (int kc = 0; kc < 4; ++kc) {
            const s8v w0 = ld_w(wb, (tap*64 + r31)*64      + kc*16 + h*8);
            const s8v w1 = ld_w(wb, (tap*64 + 32 + r31)*64 + kc*16 + h*8);
            const s8v a0 = ld_act(actb, p0,      kc*32 + h*16);
            const s8v a1 = ld_act(actb, p0 + 34, kc*32 + h*16);
            acc[0][0] = __builtin_amdgcn_mfma_f32_32x32x16_bf16(w0, a0, acc[0][0], 0,0,0);
            acc[1][0] = __builtin_amdgcn_mfma_f32_32x32x16_bf16(w1, a0, acc[1][0], 0,0,0);
            acc[0][1] = __builtin_amdgcn_mfma_f32_32x32x16_bf16(w0, a1, acc[0][1], 0,0,0);
            acc[1][1] = __builtin_amdgcn_mfma_f32_32x32x16_bf16(w1, a1, acc[1][1], 0,0,0);
        }
    }
}

// head conv GEMM (3ch image, K = tap*4+ci zero-padded to 48)
__device__ __forceinline__ void head_gemm(f16v acc[2][2], const char* imgb,
                                          const u16* hw, int r31, int h, int y0) {
    #pragma unroll
    for (int kc = 0; kc < 3; ++kc) {
        const s8v w0 = ld_w(hw, r31*64        + kc*16 + h*8);
        const s8v w1 = ld_w(hw, (32 + r31)*64 + kc*16 + h*8);
        #pragma unroll
        for (int pt = 0; pt < 2; ++pt) {
            const int y = y0 + pt;
            const int tA = kc*4 + h*2, tB = tA + 1;
            const int pA = (tA <= 8) ? (y + tA/3)*34 + r31 + (tA % 3) : 0;
            const int pB = (tB <= 8) ? (y + tB/3)*34 + r31 + (tB % 3) : 0;
            const uint2 lo = *reinterpret_cast<const uint2*>(imgb + pA*8);
            const uint2 hi = *reinterpret_cast<const uint2*>(imgb + pB*8);
            uint4 tmp; tmp.x = lo.x; tmp.y = lo.y; tmp.z = hi.x; tmp.w = hi.y;
            const s8v bf = __builtin_bit_cast(s8v, tmp);
            acc[0][pt] = __builtin_amdgcn_mfma_f32_32x32x16_bf16(w0, bf, acc[0][pt], 0,0,0);
            acc[1][pt] = __builtin_amdgcn_mfma_f32_32x32x16_bf16(w1, bf, acc[1][pt], 0,0,0);
        }
    }
}

// write acc -> act LDS (bf16, swizzled). C/D row = (reg&3)+8*(reg>>2)+4*h, col = r31
__device__ __forceinline__ void st_act(char* actb, const f16v acc[2][2],
                                       int r31, int h, int y0) {
    #pragma unroll
    for (int pt = 0; pt < 2; ++pt) {
        const int p = (y0 + pt + 1)*34 + r31 + 1;
        #pragma unroll
        for (int ot = 0; ot < 2; ++ot)
            #pragma unroll
            for (int g = 0; g < 4; ++g) {
                uint2 wv;
                wv.x = pk2(acc[ot][pt][g*4+0], acc[ot][pt][g*4+1]);
                wv.y = pk2(acc[ot][pt][g*4+2], acc[ot][pt][g*4+3]);
                *reinterpret_cast<uint2*>(actb + SWZB(p, ot*64 + g*16 + h*8)) = wv;
            }
    }
}

// ---------------- SR trunk (MFMA) --------------------------------------------
__global__ __launch_bounds__(1024) void k_sr(
    const float* __restrict__ inp,
    const float* __restrict__ head_b, const float* __restrict__ body_b,
    const float* __restrict__ tail_b,
    const u16* __restrict__ bw_head, const u16* __restrict__ bw_body,
    const u16* __restrict__ bw_tail,
    const int* __restrict__ perm, const int* __restrict__ vld,
    const int* __restrict__ expert, float* __restrict__ out)
{
    extern __shared__ char lds[];
    char* actb = lds;
    char* imgb = lds + IMG_OFF;
    const int slot = blockIdx.x, t = threadIdx.x;
    const int n = perm[slot];
    float* outp = out + (size_t)n * OUT_PER_IMG;

    if (!vld[slot]) {                       // over-capacity: zeros (float4 stores)
        float4 z; z.x = z.y = z.z = z.w = 0.f;
        float4* o4 = (float4*)outp;
        #pragma unroll
        for (int k = 0; k < 3; ++k) o4[k*1024 + t] = z;
        return;
    }
    const int e = expert[n];

    // zero act + img (incl. all pads)
    for (int i = t; i < LDS_BYTES/4; i += 1024) ((unsigned*)lds)[i] = 0u;
    __syncthreads();

    // stage image bf16 -> [pix][4]
    const float* src = inp + (size_t)n*3072;
    #pragma unroll
    for (int k = 0; k < 3; ++k) {
        const int i = t + k*1024;
        const int ci = i >> 10, p = i & 1023, y = p >> 5, x = p & 31;
        ((u16*)imgb)[((y+1)*34 + x + 1)*4 + ci] = f2bf(src[i]);
    }
    __syncthreads();

    const int lane = t & 63, wv = t >> 6;
    const int r31 = lane & 31, h = lane >> 5;
    const int y0 = wv * 2;

    const u16* hw = bw_head + e*4096;
    const float* hb = head_b + e*64;

    f16v acc[2][2];

    // ---- head
    bias_init(acc, hb, h);
    head_gemm(acc, imgb, hw, r31, h, y0);
    st_act(actb, acc, r31, h, y0);
    __syncthreads();

    // ---- body blocks
    for (int b = 0; b < NBLK; ++b) {
        const u16* wb = bw_body + (size_t)(e*NBLK + b)*9*64*64;
        bias_init(acc, body_b + (e*NBLK + b)*64, h);
        body_gemm(acc, actb, wb, r31, h, y0);
        // relu
        #pragma unroll
        for (int ot = 0; ot < 2; ++ot)
            #pragma unroll
            for (int pt = 0; pt < 2; ++pt)
                #pragma unroll
                for (int i = 0; i < 16; ++i)
                    acc[ot][pt][i] = fmaxf(acc[ot][pt][i], 0.f);
        if (b == NBLK-1) {                  // + h0 (recomputed from staged image)
            bias_add(acc, hb, h);
            head_gemm(acc, imgb, hw, r31, h, y0);
        }
        __syncthreads();                    // all reads of old act done
        st_act(actb, acc, r31, h, y0);
        __syncthreads();
    }

    // ---- tail: conv 64->12 (padded to 32) + pixel shuffle, paired float2 stores
    {
        const u16* tw = bw_tail + e*(9*32*64);
        const float* tb = tail_b + e*12;
        f16v tacc[2];
        #pragma unroll
        for (int pt = 0; pt < 2; ++pt)
            #pragma unroll
            for (int g = 0; g < 4; ++g)
                #pragma unroll
                for (int i = 0; i < 4; ++i) {
                    const int tc = g*8 + h*4 + i;
                    tacc[pt][g*4+i] = (tc < 12) ? tb[tc] : 0.f;
                }
        #pragma unroll
        for (int tap = 0; tap < 9; ++tap) {
            const int dy = tap / 3, dx = tap % 3;
            const int p0 = (y0 + dy)*34 + r31 + dx;
            #pragma unroll
            for (int kc = 0; kc < 4; ++kc) {
                const s8v twf = ld_w(tw, (tap*32 + r31)*64 + kc*16 + h*8);
                const s8v a0 = ld_act(actb, p0,      kc*32 + h*16);
                const s8v a1 = ld_act(actb, p0 + 34, kc*32 + h*16);
                tacc[0] = __builtin_amdgcn_mfma_f32_32x32x16_bf16(twf, a0, tacc[0], 0,0,0);
                tacc[1] = __builtin_amdgcn_mfma_f32_32x32x16_bf16(twf, a1, tacc[1], 0,0,0);
            }
        }
        // pixel-shuffle store: tc = g*8+h*4+i; (tc, tc+1) share (co,yo), xo = 2*r31(+1)
        #pragma unroll
        for (int pt = 0; pt < 2; ++pt) {
            const int ys = y0 + pt;
            #pragma unroll
            for (int g = 0; g < 2; ++g)
                #pragma unroll
                for (int i2 = 0; i2 < 2; ++i2) {
                    const int tc0 = g*8 + h*4 + i2*2;
                    if (tc0 < 12) {
                        const int co = tc0 >> 2;
                        const int yo = 2*ys + ((tc0 >> 1) & 1);
                        float2 v2;
                        v2.x = tacc[pt][g*4 + i2*2];
                        v2.y = tacc[pt][g*4 + i2*2 + 1];
                        *reinterpret_cast<float2*>(&outp[co*4096 + yo*64 + 2*r31]) = v2;
                    }
                }
        }
    }
}

extern "C" void kernel_launch(void* const* d_in, const int* in_sizes, int n_in,
                              void* d_out, int out_size, void* d_ws, size_t ws_size,
                              hipStream_t stream) {
    const float* inp     = (const float*)d_in[0];
    const float* cls_w1  = (const float*)d_in[1];
    const float* cls_b1  = (const float*)d_in[2];
    const float* cls_wfc = (const float*)d_in[3];
    const float* cls_bfc = (const float*)d_in[4];
    const float* head_w  = (const float*)d_in[5];
    const float* head_b  = (const float*)d_in[6];
    const float* body_w  = (const float*)d_in[7];
    const float* body_b  = (const float*)d_in[8];
    const float* tail_w  = (const float*)d_in[9];
    const float* tail_b  = (const float*)d_in[10];
    float* out = (float*)d_out;

    char* ws = (char*)d_ws;
    int* expert = (int*)(ws + WS_EXPERT);
    int* perm   = (int*)(ws + WS_PERM);
    int* vld    = (int*)(ws + WS_VLD);
    u16* bw_body = (u16*)(ws + WS_BODY);
    u16* bw_head = (u16*)(ws + WS_HEAD);
    u16* bw_tail = (u16*)(ws + WS_TAIL);

    hipFuncSetAttribute((const void*)k_sr,
                        hipFuncAttributeMaxDynamicSharedMemorySize, LDS_BYTES);

    k_prep<<<(679936 + 255)/256, 256, 0, stream>>>(head_w, body_w, tail_w,
                                                   bw_head, bw_body, bw_tail);
    k_classify<<<N_IMG, 256, 0, stream>>>(inp, cls_w1, cls_b1, cls_wfc, cls_bfc, expert);
    k_route<<<1, 256, 0, stream>>>(expert, perm, vld);
    k_sr<<<N_IMG, 1024, LDS_BYTES, stream>>>(inp, head_b, body_b, tail_b,
                                             bw_head, bw_body, bw_tail,
                                             perm, vld, expert, out);
}

// Round 5
// 494.290 us; speedup vs baseline: 14.9754x; 1.4136x over previous
//
#include <hip/hip_runtime.h>
#include <hip/hip_bf16.h>

typedef unsigned short u16;
typedef short s8v __attribute__((ext_vector_type(8)));
typedef float f16v __attribute__((ext_vector_type(16)));

#define N_IMG   2048
#define F       64
#define EXPERTS 4
#define NBLK    4
#define CAP     768
#define CLS_CH  16
#define OUT_PER_IMG (3*64*64)

// LDS layout (k_sr)
#define ACT_BYTES (1156*64*2)          // 147968: [pix 34*34][64ch] bf16, swizzled
#define IMG_OFF   ACT_BYTES
#define IMG_BYTES (1156*4*2)           // 9248: [pix][4ch] bf16 (ch3 = 0)
#define LDS_BYTES (ACT_BYTES + IMG_BYTES)   // 157216 <= 160 KiB

// act swizzle: pixel p (0..1155), channel-byte c (0..127), 16B-slot XOR
#define SWZB(p, c) (((p) << 7) + ((c) ^ (((p) & 7) << 4)))

// ws layout (bytes)
// weights stored wave-contiguous: one load instr = 64 lanes x 16B = 1KB chunk
#define WS_EXPERT   0
#define WS_PERM     8192
#define WS_VLD      16384
#define WS_BODY     24576                        // [lb][tap][kc][ot][lane][8]  16*36864 elems
#define WS_HEAD     (WS_BODY + 589824*2)         // [e][kc3][ot][lane][8]       4*3072 elems
#define WS_TAIL     (WS_HEAD + 12288*2)          // [e][tap][kc][lane][8]       4*18432 elems

__device__ __forceinline__ u16 f2bf(float v) {
    return __builtin_bit_cast(u16, __float2bfloat16(v));
}
__device__ __forceinline__ unsigned pk2(float a, float b) {
    return (unsigned)f2bf(a) | ((unsigned)f2bf(b) << 16);
}

// ---------------- weight prep: fp32 -> bf16, wave-contiguous MFMA layouts -----
// A-frag convention (validated r2-r4): lane=(h<<5)|r31 -> oc row = ot*32+r31,
// k-elems = kc*16 + h*8 + j (j=0..7).
__global__ __launch_bounds__(256) void k_prep(
    const float* __restrict__ hw, const float* __restrict__ bw,
    const float* __restrict__ tw, u16* __restrict__ oh,
    u16* __restrict__ ob, u16* __restrict__ otl)
{
    const int i = blockIdx.x * 256 + threadIdx.x;
    if (i < 589824) {                       // body
        const int j = i & 7, lane = (i >> 3) & 63, ot = (i >> 9) & 1;
        const int kc = (i >> 10) & 3, tap = (i >> 12) % 9, lb = i / 36864;
        const int oc = ot*32 + (lane & 31);
        const int ci = kc*16 + (lane >> 5)*8 + j;
        ob[i] = f2bf(bw[((lb*64 + oc)*64 + ci)*9 + tap]);
    } else if (i < 589824 + 12288) {        // head: k = tap*4+ci, zero-padded to 48
        const int i2 = i - 589824;
        const int j = i2 & 7, lane = (i2 >> 3) & 63, ot = (i2 >> 9) & 1;
        const int kc = (i2 >> 10) % 3, e = i2 / 3072;
        const int oc = ot*32 + (lane & 31);
        const int k = kc*16 + (lane >> 5)*8 + j;
        const int tap = k >> 2, ci = k & 3;
        const float v = (k < 36 && ci < 3) ? hw[((e*64 + oc)*3 + ci)*9 + tap] : 0.f;
        oh[i2] = f2bf(v);
    } else if (i < 589824 + 12288 + 73728) {  // tail: 12 oc padded to 32
        const int i2 = i - 602112;
        const int j = i2 & 7, lane = (i2 >> 3) & 63;
        const int kc = (i2 >> 9) & 3, tap = (i2 >> 11) % 9, e = i2 / 18432;
        const int oc = lane & 31;
        const int ci = kc*16 + (lane >> 5)*8 + j;
        const float v = (oc < 12) ? tw[((e*12 + oc)*64 + ci)*9 + tap] : 0.f;
        otl[i2] = f2bf(v);
    }
}

// ---------------- classifier ---------------------------------------------------
__global__ __launch_bounds__(256) void k_classify(
    const float* __restrict__ inp, const float* __restrict__ w1,
    const float* __restrict__ b1, const float* __restrict__ wfc,
    const float* __restrict__ bfc, int* __restrict__ expert)
{
    __shared__ float img[3*1024];
    __shared__ float wred[4][CLS_CH];
    __shared__ float meanf[CLS_CH];
    const int n = blockIdx.x, t = threadIdx.x;
    const float* src = inp + (size_t)n*3072;
    {
        const float4* s4 = (const float4*)src;
        float4* d4 = (float4*)img;
        for (int i = t; i < 768; i += 256) d4[i] = s4[i];
    }
    __syncthreads();

    float sums[CLS_CH];
    #pragma unroll
    for (int c = 0; c < CLS_CH; ++c) sums[c] = 0.f;

    #pragma unroll
    for (int k4 = 0; k4 < 4; ++k4) {
        const int p = t + k4*256, y = p >> 5, x = p & 31;
        float v[27];
        #pragma unroll
        for (int ci = 0; ci < 3; ++ci)
            #pragma unroll
            for (int dy = 0; dy < 3; ++dy)
                #pragma unroll
                for (int dx = 0; dx < 3; ++dx) {
                    const int py = y + dy - 1, px = x + dx - 1;
                    v[ci*9 + dy*3 + dx] =
                        ((unsigned)py < 32u && (unsigned)px < 32u)
                            ? img[ci*1024 + py*32 + px] : 0.f;
                }
        for (int c = 0; c < CLS_CH; ++c) {
            float o = b1[c];
            #pragma unroll
            for (int k = 0; k < 27; ++k) o += w1[c*27 + k] * v[k];
            sums[c] += fmaxf(o, 0.f);
        }
    }

    #pragma unroll
    for (int c = 0; c < CLS_CH; ++c) {
        float s = sums[c];
        #pragma unroll
        for (int m = 32; m >= 1; m >>= 1) s += __shfl_xor(s, m);
        sums[c] = s;
    }
    const int lane = t & 63, wv = t >> 6;
    if (lane == 0)
        #pragma unroll
        for (int c = 0; c < CLS_CH; ++c) wred[wv][c] = sums[c];
    __syncthreads();
    if (t < CLS_CH)
        meanf[t] = (wred[0][t] + wred[1][t] + wred[2][t] + wred[3][t]) * (1.0f/1024.0f);
    __syncthreads();
    if (t == 0) {
        float best = -1e30f; int bi = 0;
        for (int e = 0; e < EXPERTS; ++e) {
            float sc = bfc[e];
            for (int cc = 0; cc < CLS_CH; ++cc) sc += wfc[e*CLS_CH + cc] * meanf[cc];
            if (sc > best) { best = sc; bi = e; }   // strict >: first-max == jnp.argmax
        }
        expert[n] = bi;
    }
}

// ---------------- routing: expert-sorted permutation (wave ballot-scan) -------
__global__ __launch_bounds__(256) void k_route(
    const int* __restrict__ expert, int* __restrict__ perm, int* __restrict__ vld)
{
    __shared__ int cnt[EXPERTS];
    __shared__ int vbase[EXPERTS], obase[EXPERTS];
    const int t = threadIdx.x;
    const int wv = t >> 6, lane = t & 63;

    int my = 0;
    for (int c = 0; c < N_IMG/64; ++c) {
        const int e = expert[c*64 + lane];
        const unsigned long long m = __ballot(e == wv);
        my += (int)__popcll(m);
    }
    if (lane == 0) cnt[wv] = my;
    __syncthreads();
    if (t == 0) {
        int vb = 0;
        for (int e = 0; e < EXPERTS; ++e) {
            vbase[e] = vb; vb += (cnt[e] < CAP ? cnt[e] : CAP);
        }
        int ob = vb;
        for (int e = 0; e < EXPERTS; ++e) {
            obase[e] = ob; ob += (cnt[e] > CAP ? cnt[e] - CAP : 0);
        }
    }
    __syncthreads();

    int base = 0;
    for (int c = 0; c < N_IMG/64; ++c) {
        const int n = c*64 + lane;
        const int e = expert[n];
        const unsigned long long m = __ballot(e == wv);
        if (e == wv) {
            const int rank = base + (int)__popcll(m & ((1ull << lane) - 1ull));
            int slot, v;
            if (rank < CAP) { slot = vbase[wv] + rank;       v = 1; }
            else            { slot = obase[wv] + rank - CAP; v = 0; }
            perm[slot] = n; vld[slot] = v;
        }
        base += (int)__popcll(m);
    }
}

// ---------------- MFMA building blocks --------------------------------------
__device__ __forceinline__ s8v ld_act(const char* actb, int p, int c) {
    return *reinterpret_cast<const s8v*>(actb + SWZB(p, c));
}
__device__ __forceinline__ s8v ld_w(const u16* w, int eoff) {
    return *reinterpret_cast<const s8v*>(w + eoff);
}

__device__ __forceinline__ void bias_init(f16v acc[2][2], const float* bp, int h) {
    #pragma unroll
    for (int ot = 0; ot < 2; ++ot)
        #pragma unroll
        for (int g = 0; g < 4; ++g) {
            const float4 bv = *reinterpret_cast<const float4*>(bp + ot*32 + g*8 + h*4);
            const float* b4 = (const float*)&bv;
            #pragma unroll
            for (int i = 0; i < 4; ++i) {
                acc[ot][0][g*4+i] = b4[i];
                acc[ot][1][g*4+i] = b4[i];
            }
        }
}
__device__ __forceinline__ void bias_add(f16v acc[2][2], const float* bp, int h) {
    #pragma unroll
    for (int ot = 0; ot < 2; ++ot)
        #pragma unroll
        for (int g = 0; g < 4; ++g) {
            const float4 bv = *reinterpret_cast<const float4*>(bp + ot*32 + g*8 + h*4);
            const float* b4 = (const float*)&bv;
            #pragma unroll
            for (int i = 0; i < 4; ++i) {
                acc[ot][0][g*4+i] += b4[i];
                acc[ot][1][g*4+i] += b4[i];
            }
        }
}

// body conv GEMM: kc -> dx -> {4 row loads} -> dy {2 w loads + 4 MFMA}
// ds_reads/wave/layer: 48 (was 72); every w-load is a contiguous 1KB wave-txn.
__device__ __forceinline__ void body_gemm(f16v acc[2][2], const char* actb,
                                          const u16* wb, int lane, int y0) {
    const int r31 = lane & 31, h = lane >> 5;
    #pragma unroll
    for (int kc = 0; kc < 4; ++kc) {
        const int coff = kc*32 + h*16;
        #pragma unroll
        for (int dx = 0; dx < 3; ++dx) {
            s8v ar[4];
            #pragma unroll
            for (int r = 0; r < 4; ++r)
                ar[r] = ld_act(actb, (y0 + r)*34 + r31 + dx, coff);
            #pragma unroll
            for (int dy = 0; dy < 3; ++dy) {
                const int woff = ((dy*3 + dx)*4 + kc)*1024 + lane*8;
                const s8v w0 = ld_w(wb, woff);
                const s8v w1 = ld_w(wb, woff + 512);
                acc[0][0] = __builtin_amdgcn_mfma_f32_32x32x16_bf16(w0, ar[dy],   acc[0][0], 0,0,0);
                acc[1][0] = __builtin_amdgcn_mfma_f32_32x32x16_bf16(w1, ar[dy],   acc[1][0], 0,0,0);
                acc[0][1] = __builtin_amdgcn_mfma_f32_32x32x16_bf16(w0, ar[dy+1], acc[0][1], 0,0,0);
                acc[1][1] = __builtin_amdgcn_mfma_f32_32x32x16_bf16(w1, ar[dy+1], acc[1][1], 0,0,0);
            }
        }
    }
}

// head conv GEMM (3ch image, K = tap*4+ci zero-padded to 48)
__device__ __forceinline__ void head_gemm(f16v acc[2][2], const char* imgb,
                                          const u16* hw, int lane, int y0) {
    const int r31 = lane & 31, h = lane >> 5;
    #pragma unroll
    for (int kc = 0; kc < 3; ++kc) {
        const s8v w0 = ld_w(hw, kc*1024 + lane*8);
        const s8v w1 = ld_w(hw, kc*1024 + 512 + lane*8);
        #pragma unroll
        for (int pt = 0; pt < 2; ++pt) {
            const int y = y0 + pt;
            const int tA = kc*4 + h*2, tB = tA + 1;
            const int pA = (tA <= 8) ? (y + tA/3)*34 + r31 + (tA % 3) : 0;
            const int pB = (tB <= 8) ? (y + tB/3)*34 + r31 + (tB % 3) : 0;
            const uint2 lo = *reinterpret_cast<const uint2*>(imgb + pA*8);
            const uint2 hi = *reinterpret_cast<const uint2*>(imgb + pB*8);
            uint4 tmp; tmp.x = lo.x; tmp.y = lo.y; tmp.z = hi.x; tmp.w = hi.y;
            const s8v bf = __builtin_bit_cast(s8v, tmp);
            acc[0][pt] = __builtin_amdgcn_mfma_f32_32x32x16_bf16(w0, bf, acc[0][pt], 0,0,0);
            acc[1][pt] = __builtin_amdgcn_mfma_f32_32x32x16_bf16(w1, bf, acc[1][pt], 0,0,0);
        }
    }
}

// write acc -> act LDS (bf16, swizzled). C/D row = (reg&3)+8*(reg>>2)+4*h, col = r31
__device__ __forceinline__ void st_act(char* actb, const f16v acc[2][2],
                                       int r31, int h, int y0) {
    #pragma unroll
    for (int pt = 0; pt < 2; ++pt) {
        const int p = (y0 + pt + 1)*34 + r31 + 1;
        #pragma unroll
        for (int ot = 0; ot < 2; ++ot)
            #pragma unroll
            for (int g = 0; g < 4; ++g) {
                uint2 wv;
                wv.x = pk2(acc[ot][pt][g*4+0], acc[ot][pt][g*4+1]);
                wv.y = pk2(acc[ot][pt][g*4+2], acc[ot][pt][g*4+3]);
                *reinterpret_cast<uint2*>(actb + SWZB(p, ot*64 + g*16 + h*8)) = wv;
            }
    }
}

// ---------------- SR trunk (MFMA) --------------------------------------------
// min 4 waves/EU -> exactly 1 block/CU -> 128-VGPR budget (was 64: starved)
__global__ __launch_bounds__(1024, 4) void k_sr(
    const float* __restrict__ inp,
    const float* __restrict__ head_b, const float* __restrict__ body_b,
    const float* __restrict__ tail_b,
    const u16* __restrict__ bw_head, const u16* __restrict__ bw_body,
    const u16* __restrict__ bw_tail,
    const int* __restrict__ perm, const int* __restrict__ vld,
    const int* __restrict__ expert, float* __restrict__ out)
{
    extern __shared__ char lds[];
    char* actb = lds;
    char* imgb = lds + IMG_OFF;
    const int slot = blockIdx.x, t = threadIdx.x;
    const int n = perm[slot];
    float* outp = out + (size_t)n * OUT_PER_IMG;

    if (!vld[slot]) {
        float4 z; z.x = z.y = z.z = z.w = 0.f;
        float4* o4 = (float4*)outp;
        #pragma unroll
        for (int k = 0; k < 3; ++k) o4[k*1024 + t] = z;
        return;
    }
    const int e = expert[n];

    for (int i = t; i < LDS_BYTES/4; i += 1024) ((unsigned*)lds)[i] = 0u;
    __syncthreads();

    const float* src = inp + (size_t)n*3072;
    #pragma unroll
    for (int k = 0; k < 3; ++k) {
        const int i = t + k*1024;
        const int ci = i >> 10, p = i & 1023, y = p >> 5, x = p & 31;
        ((u16*)imgb)[((y+1)*34 + x + 1)*4 + ci] = f2bf(src[i]);
    }
    __syncthreads();

    const int lane = t & 63, wv = t >> 6;
    const int r31 = lane & 31, h = lane >> 5;
    const int y0 = wv * 2;

    const u16* hw = bw_head + e*3072;
    const float* hb = head_b + e*64;

    f16v acc[2][2];

    // ---- head
    bias_init(acc, hb, h);
    head_gemm(acc, imgb, hw, lane, y0);
    st_act(actb, acc, r31, h, y0);
    __syncthreads();

    // ---- body blocks
    for (int b = 0; b < NBLK; ++b) {
        const u16* wb = bw_body + (size_t)(e*NBLK + b)*36864;
        bias_init(acc, body_b + (e*NBLK + b)*64, h);
        body_gemm(acc, actb, wb, lane, y0);
        #pragma unroll
        for (int ot = 0; ot < 2; ++ot)
            #pragma unroll
            for (int pt = 0; pt < 2; ++pt)
                #pragma unroll
                for (int i = 0; i < 16; ++i)
                    acc[ot][pt][i] = fmaxf(acc[ot][pt][i], 0.f);
        if (b == NBLK-1) {
            bias_add(acc, hb, h);
            head_gemm(acc, imgb, hw, lane, y0);
        }
        __syncthreads();
        st_act(actb, acc, r31, h, y0);
        __syncthreads();
    }

    // ---- tail: conv 64->12 (padded to 32) + pixel shuffle, paired float2 stores
    {
        const u16* tw = bw_tail + e*18432;
        const float* tb = tail_b + e*12;
        f16v tacc[2];
        #pragma unroll
        for (int pt = 0; pt < 2; ++pt)
            #pragma unroll
            for (int g = 0; g < 4; ++g)
                #pragma unroll
                for (int i = 0; i < 4; ++i) {
                    const int tc = g*8 + h*4 + i;
                    tacc[pt][g*4+i] = (tc < 12) ? tb[tc] : 0.f;
                }
        #pragma unroll
        for (int kc = 0; kc < 4; ++kc) {
            const int coff = kc*32 + h*16;
            #pragma unroll
            for (int dx = 0; dx < 3; ++dx) {
                s8v ar[4];
                #pragma unroll
                for (int r = 0; r < 4; ++r)
                    ar[r] = ld_act(actb, (y0 + r)*34 + r31 + dx, coff);
                #pragma unroll
                for (int dy = 0; dy < 3; ++dy) {
                    const s8v twf = ld_w(tw, ((dy*3 + dx)*4 + kc)*512 + lane*8);
                    tacc[0] = __builtin_amdgcn_mfma_f32_32x32x16_bf16(twf, ar[dy],   tacc[0], 0,0,0);
                    tacc[1] = __builtin_amdgcn_mfma_f32_32x32x16_bf16(twf, ar[dy+1], tacc[1], 0,0,0);
                }
            }
        }
        #pragma unroll
        for (int pt = 0; pt < 2; ++pt) {
            const int ys = y0 + pt;
            #pragma unroll
            for (int g = 0; g < 2; ++g)
                #pragma unroll
                for (int i2 = 0; i2 < 2; ++i2) {
                    const int tc0 = g*8 + h*4 + i2*2;
                    if (tc0 < 12) {
                        const int co = tc0 >> 2;
                        const int yo = 2*ys + ((tc0 >> 1) & 1);
                        float2 v2;
                        v2.x = tacc[pt][g*4 + i2*2];
                        v2.y = tacc[pt][g*4 + i2*2 + 1];
                        *reinterpret_cast<float2*>(&outp[co*4096 + yo*64 + 2*r31]) = v2;
                    }
                }
        }
    }
}

extern "C" void kernel_launch(void* const* d_in, const int* in_sizes, int n_in,
                              void* d_out, int out_size, void* d_ws, size_t ws_size,
                              hipStream_t stream) {
    const float* inp     = (const float*)d_in[0];
    const float* cls_w1  = (const float*)d_in[1];
    const float* cls_b1  = (const float*)d_in[2];
    const float* cls_wfc = (const float*)d_in[3];
    const float* cls_bfc = (const float*)d_in[4];
    const float* head_w  = (const float*)d_in[5];
    const float* head_b  = (const float*)d_in[6];
    const float* body_w  = (const float*)d_in[7];
    const float* body_b  = (const float*)d_in[8];
    const float* tail_w  = (const float*)d_in[9];
    const float* tail_b  = (const float*)d_in[10];
    float* out = (float*)d_out;

    char* ws = (char*)d_ws;
    int* expert = (int*)(ws + WS_EXPERT);
    int* perm   = (int*)(ws + WS_PERM);
    int* vld    = (int*)(ws + WS_VLD);
    u16* bw_body = (u16*)(ws + WS_BODY);
    u16* bw_head = (u16*)(ws + WS_HEAD);
    u16* bw_tail = (u16*)(ws + WS_TAIL);

    hipFuncSetAttribute((const void*)k_sr,
                        hipFuncAttributeMaxDynamicSharedMemorySize, LDS_BYTES);

    k_prep<<<(675840 + 255)/256, 256, 0, stream>>>(head_w, body_w, tail_w,
                                                   bw_head, bw_body, bw_tail);
    k_classify<<<N_IMG, 256, 0, stream>>>(inp, cls_w1, cls_b1, cls_wfc, cls_bfc, expert);
    k_route<<<1, 256, 0, stream>>>(expert, perm, vld);
    k_sr<<<N_IMG, 1024, LDS_BYTES, stream>>>(inp, head_b, body_b, tail_b,
                                             bw_head, bw_body, bw_tail,
                                             perm, vld, expert, out);
}